// Round 2
// baseline (84.741 us; speedup 1.0000x reference)
//
#include <hip/hip_runtime.h>
#include <hip/hip_bf16.h>

#define NB 64    // batch
#define NT 128   // tokens (seq)
#define NE 4     // experts
#define ND 128   // model dim
#define NK 512   // ffn hidden dim
#define MH 32    // batch rows per block (half)

typedef __attribute__((ext_vector_type(8))) short bf16x8;
typedef __attribute__((ext_vector_type(4))) float f32x4;

__device__ __forceinline__ short f2bf(float f) {
    union { float f; unsigned u; } v; v.f = f;
    unsigned r = v.u + 0x7FFFu + ((v.u >> 16) & 1u);
    return (short)(r >> 16);
}

__device__ __forceinline__ float gelu_erf(float x) {
    return 0.5f * x * (1.0f + erff(x * 0.70710678118654752f));
}

// ---------------- router: one wave per token (4 tokens per wave via loop) ----
// gates_ws: [B*T][E] normalized gates. aux_partial: [512] per-block sums.
__global__ __launch_bounds__(256)
void moe_gates(const float* __restrict__ x,
               const float* __restrict__ rw,
               const float* __restrict__ rb,
               float* __restrict__ gates_ws,
               float* __restrict__ aux_partial)
{
    const int tid  = threadIdx.x;
    const int lane = tid & 63;
    const int wave = tid >> 6;
    __shared__ float waux[4];

    const float4 rw0 = *(const float4*)(rw + lane * 4);        // rw[lane][0..3]
    const float4 rw1 = *(const float4*)(rw + (64 + lane) * 4); // rw[lane+64][0..3]
    const float4 rbv = *(const float4*)rb;

    float aux = 0.f;
    #pragma unroll
    for (int i = 0; i < 4; ++i) {
        const int tok = (blockIdx.x * 4 + wave) * 4 + i;       // b*NT + t
        const float x0 = x[tok * ND + lane];
        const float x1 = x[tok * ND + 64 + lane];
        float p0 = x0 * rw0.x + x1 * rw1.x;
        float p1 = x0 * rw0.y + x1 * rw1.y;
        float p2 = x0 * rw0.z + x1 * rw1.z;
        float p3 = x0 * rw0.w + x1 * rw1.w;
        #pragma unroll
        for (int off = 32; off > 0; off >>= 1) {
            p0 += __shfl_xor(p0, off);
            p1 += __shfl_xor(p1, off);
            p2 += __shfl_xor(p2, off);
            p3 += __shfl_xor(p3, off);
        }
        if (lane == 0) {
            p0 = fmaxf(p0 + rbv.x, 0.f);
            p1 = fmaxf(p1 + rbv.y, 0.f);
            p2 = fmaxf(p2 + rbv.z, 0.f);
            p3 = fmaxf(p3 + rbv.w, 0.f);
            const float s   = p0 + p1 + p2 + p3;
            const float inv = 1.f / (s + 1e-9f);
            float4 g; g.x = p0 * inv; g.y = p1 * inv; g.z = p2 * inv; g.w = p3 * inv;
            *(float4*)(gates_ws + tok * NE) = g;
            aux += s * inv;
        }
    }
    if (lane == 0) waux[wave] = aux;
    __syncthreads();
    if (tid == 0)
        aux_partial[blockIdx.x] = waux[0] + waux[1] + waux[2] + waux[3];
}

// ---------------- main: one block per (t, e, batch-half); 4 waves ------------
__global__ __launch_bounds__(256, 4)
void moe_main(const float* __restrict__ x,
              const float* __restrict__ w1,
              const float* __restrict__ b1,
              const float* __restrict__ w2,
              const float* __restrict__ b2,
              const float* __restrict__ gates_ws,
              float* __restrict__ ws)
{
    const int bid  = blockIdx.x;
    const int h    = bid >> 9;          // batch half; twins (s, s+512) -> same XCD
    const int s    = bid & 511;
    const int t    = s >> 2;
    const int e    = s & 3;
    const int tid  = threadIdx.x;
    const int lane = tid & 63;
    const int wave = tid >> 6;
    const int l15  = lane & 15;
    const int l4   = lane >> 4;

    __shared__ short Hs[MH][NK + 8];    // 32 x 520 bf16 bits = 33,280 B
    __shared__ float gate_s[MH];

    if (tid < MH)
        gate_s[tid] = gates_ws[((h * MH + tid) * NT + t) * NE + e];

    // ---------------- GEMM1: wave owns 128-col N-stripe ----------------
    const float* W1 = w1 + (size_t)((t * NE + e) * ND) * NK;  // [ND][NK]
    const float* B1 = b1 + (t * NE + e) * NK;
    const int n0 = wave * 128;

    f32x4 acc[2][8];
    #pragma unroll
    for (int m = 0; m < 2; ++m)
        #pragma unroll
        for (int n = 0; n < 8; ++n) acc[m][n] = (f32x4){0.f, 0.f, 0.f, 0.f};

    #pragma unroll
    for (int ks = 0; ks < 4; ++ks) {
        const int d0 = ks * 32 + l4 * 8;
        bf16x8 afr[2];
        #pragma unroll
        for (int m = 0; m < 2; ++m) {
            const int b = h * MH + m * 16 + l15;
            const float* xp = x + (b * NT + t) * ND + d0;
            const float4 u = *(const float4*)(xp);
            const float4 v = *(const float4*)(xp + 4);
            bf16x8 a;
            a[0] = f2bf(u.x); a[1] = f2bf(u.y); a[2] = f2bf(u.z); a[3] = f2bf(u.w);
            a[4] = f2bf(v.x); a[5] = f2bf(v.y); a[6] = f2bf(v.z); a[7] = f2bf(v.w);
            afr[m] = a;
        }
        #pragma unroll
        for (int nt = 0; nt < 8; ++nt) {
            const int n = n0 + nt * 16 + l15;
            const float* wp = W1 + (size_t)d0 * NK + n;
            bf16x8 bfr;
            #pragma unroll
            for (int j = 0; j < 8; ++j) bfr[j] = f2bf(wp[(size_t)j * NK]);
            #pragma unroll
            for (int m = 0; m < 2; ++m)
                acc[m][nt] = __builtin_amdgcn_mfma_f32_16x16x32_bf16(afr[m], bfr, acc[m][nt], 0, 0, 0);
        }
    }

    // bias + exact-erf gelu -> bf16 H in LDS
    #pragma unroll
    for (int nt = 0; nt < 8; ++nt) {
        const int n = n0 + nt * 16 + l15;
        const float bb = B1[n];
        #pragma unroll
        for (int m = 0; m < 2; ++m) {
            const int row = m * 16 + l4 * 4;
            #pragma unroll
            for (int r = 0; r < 4; ++r) {
                const float hh = acc[m][nt][r] + bb;
                Hs[row + r][n] = f2bf(gelu_erf(hh));
            }
        }
    }
    __syncthreads();

    // ---------------- GEMM2: wave owns 32 output cols ----------------
    const float* W2 = w2 + (size_t)((t * NE + e) * NK) * ND;  // [NK][ND]
    const float* B2 = b2 + (t * NE + e) * ND;
    const int c0 = wave * 32;

    f32x4 acc2[2][2];
    #pragma unroll
    for (int m = 0; m < 2; ++m)
        #pragma unroll
        for (int n = 0; n < 2; ++n) acc2[m][n] = (f32x4){0.f, 0.f, 0.f, 0.f};

    #pragma unroll 4
    for (int ks = 0; ks < 16; ++ks) {
        const int k0 = ks * 32 + l4 * 8;
        bf16x8 afr[2];
        #pragma unroll
        for (int m = 0; m < 2; ++m)
            afr[m] = *(const bf16x8*)(&Hs[m * 16 + l15][k0]);
        #pragma unroll
        for (int nt = 0; nt < 2; ++nt) {
            const int c = c0 + nt * 16 + l15;
            const float* wp = W2 + (size_t)k0 * ND + c;
            bf16x8 bfr;
            #pragma unroll
            for (int j = 0; j < 8; ++j) bfr[j] = f2bf(wp[(size_t)j * ND]);
            #pragma unroll
            for (int m = 0; m < 2; ++m)
                acc2[m][nt] = __builtin_amdgcn_mfma_f32_16x16x32_bf16(afr[m], bfr, acc2[m][nt], 0, 0, 0);
        }
    }

    // gate-weighted epilogue -> ws[e][b][t][d]
    #pragma unroll
    for (int nt = 0; nt < 2; ++nt) {
        const int c = c0 + nt * 16 + l15;
        const float bb = B2[c];
        #pragma unroll
        for (int m = 0; m < 2; ++m) {
            #pragma unroll
            for (int r = 0; r < 4; ++r) {
                const int bl = m * 16 + l4 * 4 + r;
                const int b  = h * MH + bl;
                const float v = (acc2[m][nt][r] + bb) * gate_s[bl];
                ws[(size_t)(e * NB * NT + b * NT + t) * ND + c] = v;
            }
        }
    }
}

// ---------------- reduce 4 expert contributions + finalize aux ---------------
__global__ __launch_bounds__(256)
void moe_reduce(const float* __restrict__ ws,
                const float* __restrict__ aux_partial,
                float* __restrict__ out)
{
    const int i = blockIdx.x * blockDim.x + threadIdx.x;
    const int stride = NB * NT * ND / 4;
    const float4* w = (const float4*)ws;
    const float4 a = w[i];
    const float4 b = w[i + stride];
    const float4 c = w[i + 2 * stride];
    const float4 d = w[i + 3 * stride];
    float4 r;
    r.x = a.x + b.x + c.x + d.x;
    r.y = a.y + b.y + c.y + d.y;
    r.z = a.z + b.z + c.z + d.z;
    r.w = a.w + b.w + c.w + d.w;
    ((float4*)out)[i] = r;

    if (blockIdx.x == 0) {
        const int tid = threadIdx.x;
        float s = aux_partial[tid] + aux_partial[tid + 256];
        #pragma unroll
        for (int off = 32; off > 0; off >>= 1) s += __shfl_xor(s, off);
        __shared__ float wsum[4];
        if ((tid & 63) == 0) wsum[tid >> 6] = s;
        __syncthreads();
        if (tid == 0)
            out[NB * NT * ND] = (wsum[0] + wsum[1] + wsum[2] + wsum[3]) *
                                (0.01f / (NB * NT));
    }
}

// ---------------- fallback (ws too small): round-1 style, self-contained -----
__global__ __launch_bounds__(256, 2)
void moe_main_fb(const float* __restrict__ x,
                 const float* __restrict__ w1,
                 const float* __restrict__ b1,
                 const float* __restrict__ w2,
                 const float* __restrict__ b2,
                 const float* __restrict__ rw,
                 const float* __restrict__ rb,
                 float* __restrict__ out)
{
    const int blk  = blockIdx.x;
    const int t    = blk >> 2;
    const int e    = blk & 3;
    const int tid  = threadIdx.x;
    const int lane = tid & 63;
    const int wave = tid >> 6;
    const int l15  = lane & 15;
    const int l4   = lane >> 4;

    __shared__ short Hs[NB][NK + 8];
    __shared__ float gate_s[NB];

    if (tid < NB) {
        const int b = tid;
        const float* xr = x + (b * NT + t) * ND;
        float l0 = rb[0], l1 = rb[1], l2 = rb[2], l3 = rb[3];
        #pragma unroll 8
        for (int d = 0; d < ND; ++d) {
            const float xv = xr[d];
            const float* w = rw + d * NE;
            l0 += xv * w[0]; l1 += xv * w[1]; l2 += xv * w[2]; l3 += xv * w[3];
        }
        l0 = fmaxf(l0, 0.f); l1 = fmaxf(l1, 0.f); l2 = fmaxf(l2, 0.f); l3 = fmaxf(l3, 0.f);
        const float ss  = l0 + l1 + l2 + l3;
        const float inv = 1.f / (ss + 1e-9f);
        const float ge  = (e == 0) ? l0 : (e == 1) ? l1 : (e == 2) ? l2 : l3;
        gate_s[b] = ge * inv;
        if (e == 0) {
            float aux = ss * inv;
            #pragma unroll
            for (int off = 32; off > 0; off >>= 1) aux += __shfl_down(aux, off);
            if (lane == 0) atomicAdd(out + NB * NT * ND, aux * (0.01f / (NB * NT)));
        }
    }
    __syncthreads();

    const float* W1 = w1 + (size_t)((t * NE + e) * ND) * NK;
    const float* B1 = b1 + (t * NE + e) * NK;
    const int n0 = wave * 128;

    f32x4 acc[4][8];
    #pragma unroll
    for (int m = 0; m < 4; ++m)
        #pragma unroll
        for (int n = 0; n < 8; ++n) acc[m][n] = (f32x4){0.f, 0.f, 0.f, 0.f};

    #pragma unroll
    for (int ks = 0; ks < 4; ++ks) {
        const int d0 = ks * 32 + l4 * 8;
        bf16x8 afr[4];
        #pragma unroll
        for (int m = 0; m < 4; ++m) {
            const int b = m * 16 + l15;
            const float* xp = x + (b * NT + t) * ND + d0;
            const float4 u = *(const float4*)(xp);
            const float4 v = *(const float4*)(xp + 4);
            bf16x8 a;
            a[0] = f2bf(u.x); a[1] = f2bf(u.y); a[2] = f2bf(u.z); a[3] = f2bf(u.w);
            a[4] = f2bf(v.x); a[5] = f2bf(v.y); a[6] = f2bf(v.z); a[7] = f2bf(v.w);
            afr[m] = a;
        }
        #pragma unroll
        for (int nt = 0; nt < 8; ++nt) {
            const int n = n0 + nt * 16 + l15;
            const float* wp = W1 + (size_t)d0 * NK + n;
            bf16x8 bfr;
            #pragma unroll
            for (int j = 0; j < 8; ++j) bfr[j] = f2bf(wp[(size_t)j * NK]);
            #pragma unroll
            for (int m = 0; m < 4; ++m)
                acc[m][nt] = __builtin_amdgcn_mfma_f32_16x16x32_bf16(afr[m], bfr, acc[m][nt], 0, 0, 0);
        }
    }

    #pragma unroll
    for (int nt = 0; nt < 8; ++nt) {
        const int n = n0 + nt * 16 + l15;
        const float bb = B1[n];
        #pragma unroll
        for (int m = 0; m < 4; ++m) {
            const int row = m * 16 + l4 * 4;
            #pragma unroll
            for (int r = 0; r < 4; ++r) {
                const float hh = acc[m][nt][r] + bb;
                Hs[row + r][n] = f2bf(gelu_erf(hh));
            }
        }
    }
    __syncthreads();

    const float* W2 = w2 + (size_t)((t * NE + e) * NK) * ND;
    const float* B2 = b2 + (t * NE + e) * ND;
    const int c0 = wave * 32;

    f32x4 acc2[4][2];
    #pragma unroll
    for (int m = 0; m < 4; ++m)
        #pragma unroll
        for (int n = 0; n < 2; ++n) acc2[m][n] = (f32x4){0.f, 0.f, 0.f, 0.f};

    #pragma unroll 4
    for (int ks = 0; ks < 16; ++ks) {
        const int k0 = ks * 32 + l4 * 8;
        bf16x8 afr[4];
        #pragma unroll
        for (int m = 0; m < 4; ++m)
            afr[m] = *(const bf16x8*)(&Hs[m * 16 + l15][k0]);
        #pragma unroll
        for (int nt = 0; nt < 2; ++nt) {
            const int c = c0 + nt * 16 + l15;
            const float* wp = W2 + (size_t)k0 * ND + c;
            bf16x8 bfr;
            #pragma unroll
            for (int j = 0; j < 8; ++j) bfr[j] = f2bf(wp[(size_t)j * ND]);
            #pragma unroll
            for (int m = 0; m < 4; ++m)
                acc2[m][nt] = __builtin_amdgcn_mfma_f32_16x16x32_bf16(afr[m], bfr, acc2[m][nt], 0, 0, 0);
        }
    }

    #pragma unroll
    for (int nt = 0; nt < 2; ++nt) {
        const int c = c0 + nt * 16 + l15;
        const float bb = B2[c];
        #pragma unroll
        for (int m = 0; m < 4; ++m) {
            #pragma unroll
            for (int r = 0; r < 4; ++r) {
                const int b = m * 16 + l4 * 4 + r;
                const float v = (acc2[m][nt][r] + bb) * gate_s[b];
                atomicAdd(out + (size_t)(b * NT + t) * ND + c, v);
            }
        }
    }
}

extern "C" void kernel_launch(void* const* d_in, const int* in_sizes, int n_in,
                              void* d_out, int out_size, void* d_ws, size_t ws_size,
                              hipStream_t stream) {
    const float* x  = (const float*)d_in[0];
    const float* w1 = (const float*)d_in[1];
    const float* b1 = (const float*)d_in[2];
    const float* w2 = (const float*)d_in[3];
    const float* b2 = (const float*)d_in[4];
    const float* rw = (const float*)d_in[5];
    const float* rb = (const float*)d_in[6];
    float* out = (float*)d_out;

    const size_t contrib_elems = (size_t)NE * NB * NT * ND;           // 16 MiB
    const size_t gates_elems   = (size_t)NB * NT * NE;                // 128 KiB
    const size_t aux_elems     = 512;
    const size_t ws_need = (contrib_elems + gates_elems + aux_elems) * sizeof(float);

    if (ws_size >= ws_need) {
        float* contrib = (float*)d_ws;
        float* gates   = contrib + contrib_elems;
        float* auxp    = gates + gates_elems;

        moe_gates<<<512, 256, 0, stream>>>(x, rw, rb, gates, auxp);
        moe_main<<<NT * NE * 2, 256, 0, stream>>>(x, w1, b1, w2, b2, gates, contrib);
        moe_reduce<<<(NB * NT * ND / 4) / 256, 256, 0, stream>>>(contrib, auxp, out);
    } else {
        hipMemsetAsync(d_out, 0, (size_t)(NB * NT * ND + 1) * sizeof(float), stream);
        moe_main_fb<<<NT * NE, 256, 0, stream>>>(x, w1, b1, w2, b2, rw, rb, out);
    }
}